// Round 6
// baseline (304.654 us; speedup 1.0000x reference)
//
#include <hip/hip_runtime.h>
#include <hip/hip_bf16.h>

#define KK 32
#define DIN 128
#define DOUT 32
#define NVEC (KK * DOUT)        // 1024 floats per node
#define MBKT 64                 // bucket slots per row == wave size
#define OCAP 4096               // overflow capacity (never used for Poisson(16))

typedef float        vf4    __attribute__((ext_vector_type(4)));
typedef unsigned int vu4    __attribute__((ext_vector_type(4)));
typedef unsigned int vu2    __attribute__((ext_vector_type(2)));
typedef short        bf16x8 __attribute__((ext_vector_type(8)));

__device__ __forceinline__ float bfu2f(unsigned int u) {
    return __uint_as_float(u << 16);
}
__device__ __forceinline__ unsigned int f2bfu(float f) {
    __hip_bfloat16 b = __float2bfloat16(f);
    return *(unsigned short*)&b;
}

// ---------------- K2: zero cursor[N]+ocnt AND pack W fragments once ---------
// Block 0 additionally converts W (128x32 f32, 16KB) into the exact per-lane
// bf16x8 MFMA fragment order: wfrag[(nt*4+ks)*64 + lane][j] = bf16(W[k][n]),
// k = ks*32 + (lane>>4)*8 + j, n = nt*16 + (lane&15).
__global__ __launch_bounds__(256) void prep_kernel(
    int* __restrict__ p, int n,
    const float* __restrict__ w, unsigned short* __restrict__ wfrag)
{
    int i = blockIdx.x * 256 + threadIdx.x;
    if (i < n) p[i] = 0;
    if (blockIdx.x == 0) {
        for (int item = threadIdx.x; item < 512; item += 256) {
            int lane = item & 63;
            int fk   = item >> 6;          // nt*4 + ks
            int nt   = fk >> 2, ks = fk & 3;
            int q    = lane >> 4, lm = lane & 15;
            #pragma unroll
            for (int j = 0; j < 8; ++j) {
                int k = ks * 32 + q * 8 + j;
                wfrag[(size_t)item * 8 + j] =
                    (unsigned short)f2bfu(w[k * DOUT + nt * 16 + lm]);
            }
        }
    }
}

// ---------------- K1 (fused): fill_bucket (blocks < FB) + MFMA gemm ----------
// gemm: 16x16x32 bf16 MFMA, A straight from global (nontemporal, read-once),
// B fragments from the precomputed wfrag table.
// h is stored K-GROUP-MAJOR: h2[g][node][128 shorts], g = k>>2 (8 slabs of
// 2.56 MB) so K3 can pin one slab per XCD L2. Tile geometry: a wave's 16
// rows are node n = tile>>1, k-slices 16c..16c+15 (c = tile&1); C-row
// q*4+q2 has k = 16c+4q+q2 -> g = 4c+q (wave-uniform per q), krem = q2.
// Within a group-row the 32-col permute is unchanged: dword at short-offset
// krem*32 + lm*2 holds true cols {lm, lm+16} of slice k = 4g+krem.
__global__ __launch_bounds__(256) void gemm_fill_kernel(
    const float* __restrict__ x, const unsigned short* __restrict__ wfrag,
    unsigned short* __restrict__ h2,
    const int* __restrict__ erow, const int* __restrict__ ecol,
    const float* __restrict__ eval, int* __restrict__ cursor,
    uint2* __restrict__ bedge,
    int* __restrict__ ocnt, int* __restrict__ orow,
    int* __restrict__ ocol, float* __restrict__ oval,
    int E, int FB, int NN)
{
    const int tid = threadIdx.x;

    if (blockIdx.x < (unsigned)FB) {
        // ---- fill part: first in dispatch queue -> overlaps gemm's start ----
        int i = blockIdx.x * 256 + tid;
        if (i >= E) return;
        int r = __builtin_nontemporal_load(erow + i);
        int p = atomicAdd(&cursor[r], 1);
        if (p < MBKT) {
            uint2 e;
            e.x = (unsigned int)__builtin_nontemporal_load(ecol + i);
            e.y = __float_as_uint(__builtin_nontemporal_load(eval + i));
            bedge[r * MBKT + p] = e;
        } else {
            int q = atomicAdd(ocnt, 1);
            if (q < OCAP) {
                orow[q] = r;
                ocol[q] = ecol[i];
                oval[q] = eval[i];
            }
        }
        return;
    }

    // ---- gemm part ----
    const int lane = tid & 63;
    const int wid  = tid >> 6;
    const int q    = lane >> 4;           // quad 0..3
    const int lm   = lane & 15;

    // B fragments: 8 coalesced 16B loads from the 8KB wfrag table (L2-hot).
    bf16x8 bf[2][4];
    {
        const bf16x8* wf = (const bf16x8*)wfrag;
        #pragma unroll
        for (int nt = 0; nt < 2; ++nt)
            #pragma unroll
            for (int ks = 0; ks < 4; ++ks)
                bf[nt][ks] = wf[(nt * 4 + ks) * 64 + lane];
    }

    const int tile = (blockIdx.x - FB) * 4 + wid;   // 0..19999
    const int r0   = tile * 16;
    const float* xrow = x + (size_t)(r0 + lm) * DIN + q * 8;

    vf4 acc0 = {0.f, 0.f, 0.f, 0.f};
    vf4 acc1 = {0.f, 0.f, 0.f, 0.f};

    #pragma unroll
    for (int ks = 0; ks < 4; ++ks) {
        vf4 a0 = __builtin_nontemporal_load((const vf4*)(xrow + ks * 32));
        vf4 a1 = __builtin_nontemporal_load((const vf4*)(xrow + ks * 32 + 4));
        bf16x8 af;
        af[0] = (short)f2bfu(a0.x); af[1] = (short)f2bfu(a0.y);
        af[2] = (short)f2bfu(a0.z); af[3] = (short)f2bfu(a0.w);
        af[4] = (short)f2bfu(a1.x); af[5] = (short)f2bfu(a1.y);
        af[6] = (short)f2bfu(a1.z); af[7] = (short)f2bfu(a1.w);
        acc0 = __builtin_amdgcn_mfma_f32_16x16x32_bf16(af, bf[0][ks], acc0, 0, 0, 0);
        acc1 = __builtin_amdgcn_mfma_f32_16x16x32_bf16(af, bf[1][ks], acc1, 0, 0, 0);
    }

    // direct C store into the k-group-major layout: g = 4c+q, krem = q2.
    const int n  = tile >> 1;
    const int cc = tile & 1;
    unsigned short* hbase =
        h2 + ((size_t)(4 * cc + q) * NN + n) * 128 + lm * 2;
    #pragma unroll
    for (int q2 = 0; q2 < 4; ++q2) {
        unsigned int pk = f2bfu(acc0[q2]) | (f2bfu(acc1[q2]) << 16);
        *(unsigned int*)(hbase + q2 * 32) = pk;
    }
}

// ---------------- K3: XCD-sharded gather-accumulate + ReLU -------------------
// Shard at ISSUE-PARITY with the R1 structure (R4's regression was 4x the
// VMEM instruction count, not absent locality). Wave = (row, g), g=bid&7 ->
// dispatch round-robin pins slab g (2.56 MB) to one XCD's 4 MB L2; after
// first touch ~94% of the 327 MB gather is local-L2.
//   lanes: li = lane&15 owns 16B of the 256B group-row (dwordx4 kept!),
//          eg = lane>>4 processes edge j*4+eg per iteration (per-lane shfl).
//   Per row: 8 waves x 4 iters x 1 dwordx4 = 32 gather instrs == R1.
//   Tail guard-free: ev==0 for lanes >= degb -> v=0, c=0 (valid addr).
//   Combine: 2-step shfl_xor butterfly (16/32) -> all lanes hold totals.
// bedge re-read x8 (nontemporal, +36MB): the one accepted cost.
// Unpermute per group: lane li's shorts = positions 8*(li&3)+i of slice
// k=4g+(li>>2); even i -> col 4*(li&3)+i/2, odd -> +16. Lanes li<16 write.
__global__ __launch_bounds__(128) void agg_kernel(
    const unsigned short* __restrict__ h2, const int* __restrict__ cursor,
    const uint2* __restrict__ bedge,
    const int* __restrict__ ocnt, const int* __restrict__ orow,
    const int* __restrict__ ocol, const float* __restrict__ oval,
    float* __restrict__ out, int N)
{
    const int tid  = threadIdx.x;
    const int wv   = tid >> 6;
    const int lane = tid & 63;
    const int li   = lane & 15;          // position sub-lane (16B)
    const int eg   = lane >> 4;          // edge subgroup 0..3
    const int g    = blockIdx.x & 7;     // k-group == XCD
    const int r    = (blockIdx.x >> 3) * 2 + wv;
    if (r >= N) return;

    const int deg  = cursor[r];
    const int degb = deg < MBKT ? deg : MBKT;
    const int on0  = *ocnt;             // hot single line

    int   ec = 0;
    float ev = 0.f;
    if (lane < degb) {
        vu2 e = __builtin_nontemporal_load((const vu2*)bedge + r * MBKT + lane);
        ec = (int)e.x;
        ev = __uint_as_float(e.y);
    }

    const unsigned short* hg = h2 + (size_t)g * N * 128;   // this XCD's slab

    float acc[8];
    #pragma unroll
    for (int q = 0; q < 8; ++q) acc[q] = 0.f;

    const int iters = (degb + 3) >> 2;
    #pragma unroll 4
    for (int j = 0; j < iters; ++j) {
        int   idx = j * 4 + eg;                 // <= 63 always
        int   c = __shfl(ec, idx, 64);
        float v = __shfl(ev, idx, 64);          // 0 beyond degb
        vu4 p = *(const vu4*)(hg + (size_t)c * 128 + li * 8);
        acc[0] += v * bfu2f(p.x & 0xffffu);
        acc[1] += v * bfu2f(p.x >> 16);
        acc[2] += v * bfu2f(p.y & 0xffffu);
        acc[3] += v * bfu2f(p.y >> 16);
        acc[4] += v * bfu2f(p.z & 0xffffu);
        acc[5] += v * bfu2f(p.z >> 16);
        acc[6] += v * bfu2f(p.w & 0xffffu);
        acc[7] += v * bfu2f(p.w >> 16);
    }

    // cross-subgroup combine: all lanes end with the full sums
    #pragma unroll
    for (int q = 0; q < 8; ++q) {
        acc[q] += __shfl_xor(acc[q], 16, 64);
        acc[q] += __shfl_xor(acc[q], 32, 64);
    }

    // cold overflow path (correctness only; empty for this graph).
    // All lanes add identical contributions -> replicas stay consistent.
    if (on0 > 0) {
        int on = on0 > OCAP ? OCAP : on0;
        for (int q = 0; q < on; ++q) {
            if (orow[q] == r) {
                int   c = ocol[q];
                float v = oval[q];
                vu4 p = *(const vu4*)(hg + (size_t)c * 128 + li * 8);
                acc[0] += v * bfu2f(p.x & 0xffffu);
                acc[1] += v * bfu2f(p.x >> 16);
                acc[2] += v * bfu2f(p.y & 0xffffu);
                acc[3] += v * bfu2f(p.y >> 16);
                acc[4] += v * bfu2f(p.z & 0xffffu);
                acc[5] += v * bfu2f(p.z >> 16);
                acc[6] += v * bfu2f(p.w & 0xffffu);
                acc[7] += v * bfu2f(p.w >> 16);
            }
        }
    }

    // unpermute + ReLU; replicas eg=1..3 hold identical data, eg=0 writes
    if (eg == 0) {
        vf4 oA, oB;
        oA.x = fmaxf(acc[0], 0.f); oA.y = fmaxf(acc[2], 0.f);
        oA.z = fmaxf(acc[4], 0.f); oA.w = fmaxf(acc[6], 0.f);
        oB.x = fmaxf(acc[1], 0.f); oB.y = fmaxf(acc[3], 0.f);
        oB.z = fmaxf(acc[5], 0.f); oB.w = fmaxf(acc[7], 0.f);
        float* obase = out + (size_t)r * NVEC
                     + (4 * g + (li >> 2)) * 32 + (li & 3) * 4;
        __builtin_nontemporal_store(oA, (vf4*)obase);        // cols c..c+3
        __builtin_nontemporal_store(oB, (vf4*)(obase + 16)); // cols 16+c..+3
    }
}

extern "C" void kernel_launch(void* const* d_in, const int* in_sizes, int n_in,
                              void* d_out, int out_size, void* d_ws, size_t ws_size,
                              hipStream_t stream)
{
    const float* x    = (const float*)d_in[0];
    const float* w    = (const float*)d_in[1];
    const int*   erow = (const int*)d_in[2];
    const int*   ecol = (const int*)d_in[3];
    const float* eval = (const float*)d_in[4];
    float* out = (float*)d_out;

    const int E = in_sizes[2];
    const int N = in_sizes[0] / (KK * DIN);
    const int R = N * KK;

    char* ws = (char*)d_ws;
    size_t off = 0;
    auto take = [&](size_t bytes) {
        void* p = ws + off;
        off += (bytes + 15) & ~(size_t)15;
        return p;
    };
    unsigned short* h = (unsigned short*)take((size_t)R * DOUT * sizeof(unsigned short));
    int*   cursor = (int*)take((size_t)(N + 1) * sizeof(int)); // [N]=oflow_cnt
    uint2* bedge  = (uint2*)take((size_t)N * MBKT * sizeof(uint2));
    int*   orow   = (int*)take((size_t)OCAP * sizeof(int));
    int*   ocol   = (int*)take((size_t)OCAP * sizeof(int));
    float* oval   = (float*)take((size_t)OCAP * sizeof(float));
    unsigned short* wfrag = (unsigned short*)take((size_t)512 * 8 * sizeof(unsigned short));
    int*   ocnt   = cursor + N;
    (void)ws_size;

    const int FB = (E + 255) / 256;       // fill blocks (first in queue)
    const int GB = (R / 16) / 4;          // 1 tile/wave, 4 waves/block

    prep_kernel<<<(N + 1 + 255) / 256, 256, 0, stream>>>(cursor, N + 1, w, wfrag);
    gemm_fill_kernel<<<FB + GB, 256, 0, stream>>>(
        x, wfrag, h, erow, ecol, eval, cursor, bedge, ocnt, orow, ocol, oval,
        E, FB, N);
    agg_kernel<<<((N + 1) / 2) * 8, 128, 0, stream>>>(
        h, cursor, bedge, ocnt, orow, ocol, oval, out, N);
}